// Round 10
// baseline (337.417 us; speedup 1.0000x reference)
//
#include <hip/hip_runtime.h>
#include <hip/hip_bf16.h>

#define NN 100000
#define NE 1600000
#define NG 2000
#define KTOP 7
#define KCAP 192                   // per-graph key cache (max graph ~87 nodes; 20 sigma)

#define BNODES 128                 // nodes per bucket
#define NBKT 782                   // ceil(NN/128)
#define EPB 8192                   // edges per level-1 block
#define NL1B 196                   // ceil(NE/EPB)
#define L2CAP 4096                 // LDS edge capacity in level-2 build

#define GEMM_BLOCKS 768            // front gemm: grid-stride, 3 blocks/CU (49 KB LDS)
#define NTILES 1563                // ceil(NN/64)
#define SMEM_FLOATS (64 * 68 + 2 * 64 * 64)   // front: As + Bl + Br = 50176 B

#define ACC4(A, V) do { A.x += V.x; A.y += V.y; A.z += V.z; A.w += V.w; } while (0)
#define ACC4P(A, U, W) do { A.x += U.x + W.x; A.y += U.y + W.y; \
                            A.z += U.z + W.z; A.w += U.w + W.w; } while (0)

// per-node aggregate: this thread owns features [fo, fo+16); 2-edge unroll = 8 loads in flight
__device__ __forceinline__ void agg_node(const float* __restrict__ XLp, const int* __restrict__ ce,
        int s, int e, int fo, float4& a0, float4& a1, float4& a2, float4& a3) {
    int a = s;
    for (; a + 2 <= e; a += 2) {
        const float4* p0 = (const float4*)(XLp + ((size_t)ce[a] << 6) + fo);
        const float4* p1 = (const float4*)(XLp + ((size_t)ce[a + 1] << 6) + fo);
        float4 u0 = p0[0], u1 = p0[1], u2 = p0[2], u3 = p0[3];
        float4 w0 = p1[0], w1 = p1[1], w2 = p1[2], w3 = p1[3];
        ACC4P(a0, u0, w0); ACC4P(a1, u1, w1); ACC4P(a2, u2, w2); ACC4P(a3, u3, w3);
    }
    if (a < e) {
        const float4* p0 = (const float4*)(XLp + ((size_t)ce[a] << 6) + fo);
        float4 u0 = p0[0], u1 = p0[1], u2 = p0[2], u3 = p0[3];
        ACC4(a0, u0); ACC4(a1, u1); ACC4(a2, u2); ACC4(a3, u3);
    }
}

// relu(mean + residual) on 4x float4 — formula must stay bit-identical across kernels
__device__ __forceinline__ void relu_mean_res(float inv, const float4* tp,
        float4& h0, float4& h1, float4& h2, float4& h3) {
    float4 t0 = tp[0], t1 = tp[1], t2 = tp[2], t3 = tp[3];
    h0.x = fmaxf(h0.x * inv + t0.x, 0.f); h0.y = fmaxf(h0.y * inv + t0.y, 0.f);
    h0.z = fmaxf(h0.z * inv + t0.z, 0.f); h0.w = fmaxf(h0.w * inv + t0.w, 0.f);
    h1.x = fmaxf(h1.x * inv + t1.x, 0.f); h1.y = fmaxf(h1.y * inv + t1.y, 0.f);
    h1.z = fmaxf(h1.z * inv + t1.z, 0.f); h1.w = fmaxf(h1.w * inv + t1.w, 0.f);
    h2.x = fmaxf(h2.x * inv + t2.x, 0.f); h2.y = fmaxf(h2.y * inv + t2.y, 0.f);
    h2.z = fmaxf(h2.z * inv + t2.z, 0.f); h2.w = fmaxf(h2.w * inv + t2.w, 0.f);
    h3.x = fmaxf(h3.x * inv + t3.x, 0.f); h3.y = fmaxf(h3.y * inv + t3.y, 0.f);
    h3.z = fmaxf(h3.z * inv + t3.z, 0.f); h3.w = fmaxf(h3.w * inv + t3.w, 0.f);
}

// key for node i from packed col-63 arrays; order matches agg_node's .w lane exactly
__device__ __forceinline__ float compute_key(int i, const float* __restrict__ keycol,
        const float* __restrict__ tcol, const int* __restrict__ ptr,
        const int* __restrict__ ce) {
    int s = ptr[i], e = ptr[i + 1];
    float acc = 0.f;
    int a = s;
    for (; a + 2 <= e; a += 2) acc += keycol[ce[a]] + keycol[ce[a + 1]];
    if (a < e) acc += keycol[ce[a]];
    float inv = 1.f / fmaxf((float)(e - s), 1.f);
    return fmaxf(acc * inv + tcol[i], 0.f);
}

#define FMA4C(av, B, acc) do { \
    acc[0] = fmaf(av, B.x, acc[0]); acc[1] = fmaf(av, B.y, acc[1]); \
    acc[2] = fmaf(av, B.z, acc[2]); acc[3] = fmaf(av, B.w, acc[3]); } while (0)

// dual GEMM tile, LDS A + LDS weights (front kernel)
__device__ __forceinline__ void gemm_tile(const float* As, const float* Bl, const float* Br,
        int n0, int ty4, int tx4, float b0, float b1v, float b2v, float b3v,
        float* __restrict__ XL, float* __restrict__ T,
        float* __restrict__ kc_out, float* __restrict__ tc_out) {
    float accl[4][4] = {{0.f}}, accr[4][4] = {{0.f}};
    for (int kc = 0; kc < 64; kc += 4) {
        float4 Av[4], L[4], R[4];
        #pragma unroll
        for (int i = 0; i < 4; ++i) Av[i] = *(const float4*)&As[(ty4 + i) * 68 + kc];
        #pragma unroll
        for (int j = 0; j < 4; ++j) {
            L[j] = *(const float4*)&Bl[(kc + j) * 64 + tx4];
            R[j] = *(const float4*)&Br[(kc + j) * 64 + tx4];
        }
        #pragma unroll
        for (int i = 0; i < 4; ++i) {
            FMA4C(Av[i].x, L[0], accl[i]); FMA4C(Av[i].y, L[1], accl[i]);
            FMA4C(Av[i].z, L[2], accl[i]); FMA4C(Av[i].w, L[3], accl[i]);
            FMA4C(Av[i].x, R[0], accr[i]); FMA4C(Av[i].y, R[1], accr[i]);
            FMA4C(Av[i].z, R[2], accr[i]); FMA4C(Av[i].w, R[3], accr[i]);
        }
    }
    #pragma unroll
    for (int i = 0; i < 4; ++i) {
        int g = n0 + ty4 + i;
        if (g < NN) {
            *(float4*)&XL[(size_t)g * 64 + tx4] =
                make_float4(accl[i][0], accl[i][1], accl[i][2], accl[i][3]);
            *(float4*)&T[(size_t)g * 64 + tx4] =
                make_float4(accr[i][0] + b0, accr[i][1] + b1v, accr[i][2] + b2v, accr[i][3] + b3v);
            if (kc_out && tx4 == 60) {
                kc_out[g] = accl[i][3];
                tc_out[g] = accr[i][3] + b3v;
            }
        }
    }
}

__device__ __forceinline__ void stage_weights(float* Bl, float* Br,
        const float* __restrict__ Wl, const float* __restrict__ Wr, int t) {
    #pragma unroll
    for (int q = 0; q < 4; ++q) {
        int idx = t + q * 256;
        ((float4*)Bl)[idx] = ((const float4*)Wl)[idx];
        ((float4*)Br)[idx] = ((const float4*)Wr)[idx];
    }
}

__device__ __forceinline__ void gemm_body(int bid, int nblocks, float* smem,
        const float* __restrict__ X, const float* __restrict__ Wl,
        const float* __restrict__ Wr, const float* __restrict__ bias,
        float* __restrict__ XL, float* __restrict__ T) {
    float* As = smem;
    float* Bl = smem + 64 * 68;
    float* Br = Bl + 64 * 64;
    int t = threadIdx.x;
    stage_weights(Bl, Br, Wl, Wr, t);
    int ty4 = (t >> 4) * 4, tx4 = (t & 15) * 4;
    float b0 = bias[tx4 + 0], b1v = bias[tx4 + 1], b2v = bias[tx4 + 2], b3v = bias[tx4 + 3];
    for (int tile = bid; tile < NTILES; tile += nblocks) {
        int n0 = tile * 64;
        #pragma unroll
        for (int q = 0; q < 4; ++q) {
            int f = t + q * 256;
            int node = f >> 4, seg = f & 15;
            int g = n0 + node;
            float4 v = make_float4(0.f, 0.f, 0.f, 0.f);
            if (g < NN) v = *(const float4*)&X[(size_t)g * 64 + seg * 4];
            *(float4*)&As[node * 68 + seg * 4] = v;
        }
        __syncthreads();
        gemm_tile(As, Bl, Br, n0, ty4, tx4, b0, b1v, b2v, b3v, XL, T, nullptr, nullptr);
        __syncthreads();
    }
}

// ---------------- fused aggregate + dual GEMM, occupancy-first variant ----------------
// LDS = As only (17.4 KB); weights read per-kc from global (L1/L2-hot, 16-lane broadcast);
// no VGPR cap (R6's (256,6)->40-reg spills are the known trap). 1 tile/block.
__global__ __launch_bounds__(256) void k_aggemm(const float* __restrict__ XL_in,
        float* __restrict__ T, const int* __restrict__ ptr, const int* __restrict__ ce,
        const float* __restrict__ Wl, const float* __restrict__ Wr,
        const float* __restrict__ bias, float* __restrict__ XL_out,
        float* __restrict__ kc_out, float* __restrict__ tc_out) {
    __shared__ float As[64 * 68];
    int t = threadIdx.x;
    int node_l = t >> 2;           // 0..63
    int fo = (t & 3) * 16;
    int n0 = blockIdx.x * 64;
    int i = n0 + node_l;
    float4 h0 = make_float4(0.f, 0.f, 0.f, 0.f), h1 = h0, h2 = h0, h3 = h0;
    if (i < NN) {
        int s = ptr[i], e = ptr[i + 1];
        agg_node(XL_in, ce, s, e, fo, h0, h1, h2, h3);
        float inv = 1.f / fmaxf((float)(e - s), 1.f);
        relu_mean_res(inv, (const float4*)(T + ((size_t)i << 6) + fo), h0, h1, h2, h3);
    }
    float* dst = &As[node_l * 68 + fo];
    ((float4*)dst)[0] = h0; ((float4*)dst)[1] = h1;
    ((float4*)dst)[2] = h2; ((float4*)dst)[3] = h3;
    __syncthreads();
    int ty4 = (t >> 4) * 4, tx4 = (t & 15) * 4;
    float b0 = bias[tx4 + 0], b1v = bias[tx4 + 1], b2v = bias[tx4 + 2], b3v = bias[tx4 + 3];
    float accl[4][4] = {{0.f}}, accr[4][4] = {{0.f}};
    for (int kc = 0; kc < 64; kc += 4) {
        float4 Av[4], L[4], R[4];
        #pragma unroll
        for (int ii = 0; ii < 4; ++ii) Av[ii] = *(const float4*)&As[(ty4 + ii) * 68 + kc];
        #pragma unroll
        for (int j = 0; j < 4; ++j) {
            L[j] = *(const float4*)&Wl[(kc + j) * 64 + tx4];   // L1/L2-hot broadcast
            R[j] = *(const float4*)&Wr[(kc + j) * 64 + tx4];
        }
        #pragma unroll
        for (int ii = 0; ii < 4; ++ii) {
            FMA4C(Av[ii].x, L[0], accl[ii]); FMA4C(Av[ii].y, L[1], accl[ii]);
            FMA4C(Av[ii].z, L[2], accl[ii]); FMA4C(Av[ii].w, L[3], accl[ii]);
            FMA4C(Av[ii].x, R[0], accr[ii]); FMA4C(Av[ii].y, R[1], accr[ii]);
            FMA4C(Av[ii].z, R[2], accr[ii]); FMA4C(Av[ii].w, R[3], accr[ii]);
        }
    }
    #pragma unroll
    for (int ii = 0; ii < 4; ++ii) {
        int g = n0 + ty4 + ii;
        if (g < NN) {
            *(float4*)&XL_out[(size_t)g * 64 + tx4] =
                make_float4(accl[ii][0], accl[ii][1], accl[ii][2], accl[ii][3]);
            *(float4*)&T[(size_t)g * 64 + tx4] =
                make_float4(accr[ii][0] + b0, accr[ii][1] + b1v, accr[ii][2] + b2v, accr[ii][3] + b3v);
            if (kc_out && tx4 == 60) {
                kc_out[g] = accl[ii][3];
                tc_out[g] = accr[ii][3] + b3v;
            }
        }
    }
}

// ---------------- front mega-kernel: gemm1 || bucket-count(transposed) || gstart ----------------
__global__ __launch_bounds__(256) void k_front(const float* __restrict__ X,
        const float* __restrict__ Wl, const float* __restrict__ Wr,
        const float* __restrict__ bias, float* __restrict__ XL, float* __restrict__ T,
        const int* __restrict__ edst, int* __restrict__ bh_t,
        const int* __restrict__ bat, int* __restrict__ gstart) {
    __shared__ float smem[SMEM_FLOATS];
    int bid = blockIdx.x, t = threadIdx.x;
    if (bid < GEMM_BLOCKS) {
        gemm_body(bid, GEMM_BLOCKS, smem, X, Wl, Wr, bias, XL, T);
    } else if (bid < GEMM_BLOCKS + NL1B) {
        int bk = bid - GEMM_BLOCKS;
        int* h = (int*)smem;
        for (int q = t; q < NBKT; q += 256) h[q] = 0;
        __syncthreads();
        int e0 = bk * EPB, e1 = min(e0 + EPB, NE);
        for (int e = e0 + t; e < e1; e += 256) atomicAdd(&h[edst[e] >> 7], 1);
        __syncthreads();
        for (int q = t; q < NBKT; q += 256) bh_t[q * NL1B + bk] = h[q];   // transposed
    } else {
        int g = (bid - GEMM_BLOCKS - NL1B) * 256 + t;
        if (g <= NG) {
            int lo = 0, hi = NN;
            while (lo < hi) { int mid = (lo + hi) >> 1; if (bat[mid] < g) lo = mid + 1; else hi = mid; }
            gstart[g] = lo;
        }
    }
}

// per-bucket scan across NL1B blocks — contiguous reads
__global__ void k_colscan(int* __restrict__ bh_t, int* __restrict__ btot) {
    __shared__ int carry;
    int b = blockIdx.x, t = threadIdx.x;    // 64 threads
    if (t == 0) carry = 0;
    __syncthreads();
    for (int base = 0; base < NL1B; base += 64) {
        int idx = base + t;
        int v = (idx < NL1B) ? bh_t[b * NL1B + idx] : 0;
        int x = v;
        #pragma unroll
        for (int off = 1; off < 64; off <<= 1) {
            int y = __shfl_up(x, off);
            if (t >= off) x += y;
        }
        int c = carry;
        if (idx < NL1B) bh_t[b * NL1B + idx] = c + x - v;   // exclusive partial
        __syncthreads();
        if (t == 63) carry = c + x;
        __syncthreads();
    }
    if (t == 0) btot[b] = carry;
}

// level-1 scatter: computes bstart scan in-LDS from btot
__global__ __launch_bounds__(256) void k_bscatter(const int* __restrict__ esrc,
        const int* __restrict__ edst, const int* __restrict__ bh_t,
        const int* __restrict__ btot, int* __restrict__ ebuf) {
    __shared__ int sbt[1024];
    __shared__ int ssum[256];
    __shared__ int cur[NBKT];
    int t = threadIdx.x, bk = blockIdx.x;
    for (int q = t; q < 1024; q += 256) sbt[q] = (q < NBKT) ? btot[q] : 0;
    __syncthreads();
    int base = t * 4;
    int a0 = sbt[base], a1 = sbt[base + 1], a2 = sbt[base + 2], a3 = sbt[base + 3];
    int s1 = a0 + a1, s2 = s1 + a2, s3 = s2 + a3;
    ssum[t] = s3;
    __syncthreads();
    for (int off = 1; off < 256; off <<= 1) {
        int y = (t >= off) ? ssum[t - off] : 0;
        __syncthreads();
        ssum[t] += y;
        __syncthreads();
    }
    int prev = (t > 0) ? ssum[t - 1] : 0;
    sbt[base] = prev; sbt[base + 1] = prev + a0;
    sbt[base + 2] = prev + s1; sbt[base + 3] = prev + s2;
    __syncthreads();
    for (int q = t; q < NBKT; q += 256) cur[q] = sbt[q] + bh_t[q * NL1B + bk];
    __syncthreads();
    int e0 = bk * EPB, e1 = min(e0 + EPB, NE);
    for (int e = e0 + t; e < e1; e += 256) {
        int d = edst[e], s = esrc[e];
        int pos = atomicAdd(&cur[d >> 7], 1);
        ebuf[pos] = s | ((d & 127) << 20);
    }
}

// level-2: per-bucket count/scan/place/sort in LDS; bstart prefix computed in-block
__global__ __launch_bounds__(128) void k_bbuild(const int* __restrict__ ebuf,
        const int* __restrict__ btot, int* __restrict__ ce, int* __restrict__ ptr) {
    __shared__ int lord[L2CAP];
    __shared__ int cnt[BNODES], sc[BNODES], cursor[BNODES];
    __shared__ int red[128];
    int b = blockIdx.x, t = threadIdx.x;     // 128 threads
    int part = 0;
    for (int j = t; j < b; j += 128) part += btot[j];
    red[t] = part;
    __syncthreads();
    for (int off = 64; off >= 1; off >>= 1) {
        if (t < off) red[t] += red[t + off];
        __syncthreads();
    }
    int base = red[0];
    int nb = btot[b];
    cnt[t] = 0;
    __syncthreads();
    for (int j = t; j < nb; j += 128) atomicAdd(&cnt[ebuf[base + j] >> 20], 1);
    __syncthreads();
    int v = cnt[t]; sc[t] = v; __syncthreads();
    for (int off = 1; off < 128; off <<= 1) {
        int y = (t >= off) ? sc[t - off] : 0;
        __syncthreads();
        sc[t] += y;
        __syncthreads();
    }
    int segend = sc[t], segstart = sc[t] - v;
    cursor[t] = segstart;
    __syncthreads();
    bool fits = (nb <= L2CAP);
    for (int j = t; j < nb; j += 128) {
        int pv = ebuf[base + j];
        int node = pv >> 20;
        int pos = atomicAdd(&cursor[node], 1);
        if (fits) lord[pos] = pv & 0xFFFFF;
        else ce[base + pos] = pv & 0xFFFFF;
    }
    __syncthreads();
    if (fits) {
        for (int a = segstart + 1; a < segend; ++a) {
            int val = lord[a]; int j = a - 1;
            while (j >= segstart && lord[j] > val) { lord[j + 1] = lord[j]; --j; }
            lord[j + 1] = val;
        }
        __syncthreads();
        for (int j = t; j < nb; j += 128) ce[base + j] = lord[j];
    } else {
        for (int a = segstart + 1; a < segend; ++a) {
            int val = ce[base + a]; int j = a - 1;
            while (j >= segstart && ce[base + j] > val) { ce[base + j + 1] = ce[base + j]; --j; }
            ce[base + j + 1] = val;
        }
    }
    int node = b * BNODES + t;
    if (node <= NN) ptr[node] = base + segstart;
}

// ---------------- tail: key + top-7 + winner-row aggregate + head, fully fused ----------------
__global__ __launch_bounds__(256) void k_tail(const int* __restrict__ gstart,
        const float* __restrict__ keycol, const float* __restrict__ tcol,
        const int* __restrict__ ptr, const int* __restrict__ ce,
        const float* __restrict__ XLa, const float* __restrict__ T,
        const float* __restrict__ cw, const float* __restrict__ cb,
        const float* __restrict__ l1w, const float* __restrict__ l1b,
        const float* __restrict__ l2w, const float* __restrict__ l2b,
        float* __restrict__ out, int G) {
    __shared__ float sw[32 * 64 * 3];
    __shared__ float s2w[64 * 10];
    __shared__ float sg[4][KTOP][64];
    __shared__ float sflat[4][160];
    __shared__ float sh1[4][64];
    __shared__ float slog[4][10];
    __shared__ float skey[4][KCAP];
    __shared__ int   widx[4][KTOP];
    int t = threadIdx.x;
    for (int q = t; q < 32 * 64 * 3; q += 256) sw[q] = cw[q];
    for (int q = t; q < 640; q += 256) s2w[q] = l2w[q];
    int wv = t >> 6, lane = t & 63;
    int b = blockIdx.x * 4 + wv;
    int s = gstart[b], e = gstart[b + 1];
    int cnt = e - s;
    for (int base = 0; base < cnt; base += 64) {
        int o = base + lane;
        if (o < cnt && o < KCAP) skey[wv][o] = compute_key(s + o, keycol, tcol, ptr, ce);
    }
    {
        float pk = 3.4e38f; int pi = -1;
        for (int r = 0; r < KTOP; ++r) {
            float bk = -1.f; int bi = -1;
            for (int o = lane; o < cnt; o += 64) {
                int i = s + o;
                float k = (o < KCAP) ? skey[wv][o] : compute_key(i, keycol, tcol, ptr, ce);
                bool elig = (k < pk) || (k == pk && i > pi);
                if (elig && (k > bk || (k == bk && (unsigned)i < (unsigned)bi))) { bk = k; bi = i; }
            }
            #pragma unroll
            for (int off = 1; off < 64; off <<= 1) {
                float ok = __shfl_xor(bk, off);
                int   oi = __shfl_xor(bi, off);
                if (ok > bk || (ok == bk && (unsigned)oi < (unsigned)bi)) { bk = ok; bi = oi; }
            }
            if (lane == 0) widx[wv][r] = bi;
            pk = bk; pi = bi;
        }
    }
    if (lane < 28) {
        int r = lane >> 2, fo = (lane & 3) * 16;
        int i = widx[wv][r];
        float4 h0 = make_float4(0.f, 0.f, 0.f, 0.f), h1 = h0, h2 = h0, h3 = h0;
        if (i >= 0) {
            int s2 = ptr[i], e2 = ptr[i + 1];
            agg_node(XLa, ce, s2, e2, fo, h0, h1, h2, h3);
            float inv = 1.f / fmaxf((float)(e2 - s2), 1.f);
            relu_mean_res(inv, (const float4*)(T + ((size_t)i << 6) + fo), h0, h1, h2, h3);
        }
        float* dstp = &sg[wv][r][fo];
        ((float4*)dstp)[0] = h0; ((float4*)dstp)[1] = h1;
        ((float4*)dstp)[2] = h2; ((float4*)dstp)[3] = h3;
    }
    __syncthreads();
    for (int idx = lane; idx < 160; idx += 64) {
        int o = idx / 5, p = idx % 5;
        float acc = cb[o];
        #pragma unroll
        for (int dt = 0; dt < 3; ++dt) {
            const float* wrow = &sw[(o * 64) * 3 + dt];
            const float* grow = &sg[wv][p + dt][0];
            for (int i = 0; i < 64; ++i) acc = fmaf(wrow[i * 3], grow[i], acc);
        }
        sflat[wv][idx] = fmaxf(acc, 0.f);
    }
    __syncthreads();
    {
        float acc = l1b[lane];
        for (int k = 0; k < 160; ++k) acc = fmaf(sflat[wv][k], l1w[k * 64 + lane], acc);
        sh1[wv][lane] = fmaxf(acc, 0.f);
    }
    __syncthreads();
    if (lane < 10) {
        float acc = l2b[lane];
        for (int k = 0; k < 64; ++k) acc = fmaf(sh1[wv][k], s2w[k * 10 + lane], acc);
        slog[wv][lane] = acc;
    }
    __syncthreads();
    if (lane < 10) {
        float m = -3.4e38f;
        for (int j = 0; j < 10; ++j) m = fmaxf(m, slog[wv][j]);
        float ssum = 0.f;
        for (int j = 0; j < 10; ++j) ssum += expf(slog[wv][j] - m);
        out[b * 10 + lane] = slog[wv][lane] - m - logf(ssum);
    }
}

extern "C" void kernel_launch(void* const* d_in, const int* in_sizes, int n_in,
                              void* d_out, int out_size, void* d_ws, size_t ws_size,
                              hipStream_t stream) {
    const float* x   = (const float*)d_in[0];
    const int*   ei  = (const int*)d_in[1];
    const int*   bat = (const int*)d_in[2];
    const float* W1l = (const float*)d_in[3], *b1 = (const float*)d_in[4], *W1r = (const float*)d_in[5];
    const float* W2l = (const float*)d_in[6], *b2 = (const float*)d_in[7], *W2r = (const float*)d_in[8];
    const float* W3l = (const float*)d_in[9], *b3 = (const float*)d_in[10], *W3r = (const float*)d_in[11];
    const float* cw  = (const float*)d_in[12], *cb  = (const float*)d_in[13];
    const float* l1w = (const float*)d_in[14], *l1b = (const float*)d_in[15];
    const float* l2w = (const float*)d_in[16], *l2b = (const float*)d_in[17];
    float* out = (float*)d_out;
    const int* esrc = ei;
    const int* edst = ei + NE;

    char* w = (char*)d_ws;
    size_t off = 0;
    auto take = [&](size_t bytes) { void* p = w + off; off = (off + bytes + 255) & ~(size_t)255; return p; };
    int*   bh_t    = (int*)take((size_t)NBKT * NL1B * 4);
    int*   btot    = (int*)take((size_t)NBKT * 4);
    int*   gstart  = (int*)take((size_t)(NG + 1) * 4);
    int*   ebuf    = (int*)take((size_t)NE * 4);
    int*   csr_ptr = (int*)take((size_t)(NN + 1) * 4);
    int*   csr_e   = (int*)take((size_t)NE * 4);
    float* XLa     = (float*)take((size_t)NN * 64 * 4);
    float* XLb     = (float*)take((size_t)NN * 64 * 4);
    float* T       = (float*)take((size_t)NN * 64 * 4);   // residual, in place
    float* keycol  = (float*)take((size_t)NN * 4);        // XLa col 63, packed
    float* tcol    = (float*)take((size_t)NN * 4);        // T col 63, packed

    // gemm1 || bucket-count || gstart
    k_front<<<GEMM_BLOCKS + NL1B + 8, 256, 0, stream>>>(x, W1l, W1r, b1, XLa, T,
                                                        edst, bh_t, bat, gstart);
    k_colscan<<<NBKT, 64, 0, stream>>>(bh_t, btot);
    k_bscatter<<<NL1B, 256, 0, stream>>>(esrc, edst, bh_t, btot, ebuf);
    k_bbuild <<<NBKT, 128, 0, stream>>>(ebuf, btot, csr_e, csr_ptr);

    // layer boundaries: aggregate (H in LDS) + dual gemm; T updated in place
    k_aggemm<<<NTILES, 256, 0, stream>>>(XLa, T, csr_ptr, csr_e, W2l, W2r, b2, XLb,
                                         nullptr, nullptr);
    k_aggemm<<<NTILES, 256, 0, stream>>>(XLb, T, csr_ptr, csr_e, W3l, W3r, b3, XLa,
                                         keycol, tcol);

    // key + top-7 + winner aggregate + head, one kernel
    k_tail<<<NG / 4, 256, 0, stream>>>(gstart, keycol, tcol, csr_ptr, csr_e, XLa, T,
                                       cw, cb, l1w, l1b, l2w, l2b, out, NG);
}

// Round 11
// 333.301 us; speedup vs baseline: 1.0123x; 1.0123x over previous
//
#include <hip/hip_runtime.h>
#include <hip/hip_bf16.h>

#define NN 100000
#define NE 1600000
#define NG 2000
#define KTOP 7
#define KCAP 192                   // per-graph key cache (max graph ~87 nodes)

#define BNODES 128                 // nodes per bucket
#define NBKT 782                   // ceil(NN/128)
#define EPB 4096                   // edges per level-1 block
#define NL1B 391                   // ceil(NE/EPB)
#define L2CAP 4096                 // LDS edge capacity in level-2 build

#define GEMM_BLOCKS 768            // aggemm grid-stride
#define GB_HALF 512                // gemm1 blocks co-running with CSR stages
#define NTILES 1563                // ceil(NN/64)
#define TSPLIT 900                 // gemm1 tile split between k3 and k4
#define SMEM_FLOATS (64 * 68 + 2 * 64 * 64)   // As + Bl + Br = 50176 B

#define ACC4(A, V) do { A.x += V.x; A.y += V.y; A.z += V.z; A.w += V.w; } while (0)
#define ACC4P(A, U, W) do { A.x += U.x + W.x; A.y += U.y + W.y; \
                            A.z += U.z + W.z; A.w += U.w + W.w; } while (0)

__device__ __forceinline__ void agg_node(const float* __restrict__ XLp, const int* __restrict__ ce,
        int s, int e, int fo, float4& a0, float4& a1, float4& a2, float4& a3) {
    int a = s;
    for (; a + 2 <= e; a += 2) {
        const float4* p0 = (const float4*)(XLp + ((size_t)ce[a] << 6) + fo);
        const float4* p1 = (const float4*)(XLp + ((size_t)ce[a + 1] << 6) + fo);
        float4 u0 = p0[0], u1 = p0[1], u2 = p0[2], u3 = p0[3];
        float4 w0 = p1[0], w1 = p1[1], w2 = p1[2], w3 = p1[3];
        ACC4P(a0, u0, w0); ACC4P(a1, u1, w1); ACC4P(a2, u2, w2); ACC4P(a3, u3, w3);
    }
    if (a < e) {
        const float4* p0 = (const float4*)(XLp + ((size_t)ce[a] << 6) + fo);
        float4 u0 = p0[0], u1 = p0[1], u2 = p0[2], u3 = p0[3];
        ACC4(a0, u0); ACC4(a1, u1); ACC4(a2, u2); ACC4(a3, u3);
    }
}

__device__ __forceinline__ void relu_mean_res(float inv, const float4* tp,
        float4& h0, float4& h1, float4& h2, float4& h3) {
    float4 t0 = tp[0], t1 = tp[1], t2 = tp[2], t3 = tp[3];
    h0.x = fmaxf(h0.x * inv + t0.x, 0.f); h0.y = fmaxf(h0.y * inv + t0.y, 0.f);
    h0.z = fmaxf(h0.z * inv + t0.z, 0.f); h0.w = fmaxf(h0.w * inv + t0.w, 0.f);
    h1.x = fmaxf(h1.x * inv + t1.x, 0.f); h1.y = fmaxf(h1.y * inv + t1.y, 0.f);
    h1.z = fmaxf(h1.z * inv + t1.z, 0.f); h1.w = fmaxf(h1.w * inv + t1.w, 0.f);
    h2.x = fmaxf(h2.x * inv + t2.x, 0.f); h2.y = fmaxf(h2.y * inv + t2.y, 0.f);
    h2.z = fmaxf(h2.z * inv + t2.z, 0.f); h2.w = fmaxf(h2.w * inv + t2.w, 0.f);
    h3.x = fmaxf(h3.x * inv + t3.x, 0.f); h3.y = fmaxf(h3.y * inv + t3.y, 0.f);
    h3.z = fmaxf(h3.z * inv + t3.z, 0.f); h3.w = fmaxf(h3.w * inv + t3.w, 0.f);
}

__device__ __forceinline__ float compute_key(int i, const float* __restrict__ keycol,
        const float* __restrict__ tcol, const int* __restrict__ ptr,
        const int* __restrict__ ce) {
    int s = ptr[i], e = ptr[i + 1];
    float acc = 0.f;
    int a = s;
    for (; a + 2 <= e; a += 2) acc += keycol[ce[a]] + keycol[ce[a + 1]];
    if (a < e) acc += keycol[ce[a]];
    float inv = 1.f / fmaxf((float)(e - s), 1.f);
    return fmaxf(acc * inv + tcol[i], 0.f);
}

#define FMA4C(av, B, acc) do { \
    acc[0] = fmaf(av, B.x, acc[0]); acc[1] = fmaf(av, B.y, acc[1]); \
    acc[2] = fmaf(av, B.z, acc[2]); acc[3] = fmaf(av, B.w, acc[3]); } while (0)

__device__ __forceinline__ void gemm_tile(const float* As, const float* Bl, const float* Br,
        int n0, int ty4, int tx4, float b0, float b1v, float b2v, float b3v,
        float* __restrict__ XL, float* __restrict__ T,
        float* __restrict__ kc_out, float* __restrict__ tc_out) {
    float accl[4][4] = {{0.f}}, accr[4][4] = {{0.f}};
    for (int kc = 0; kc < 64; kc += 4) {
        float4 Av[4], L[4], R[4];
        #pragma unroll
        for (int i = 0; i < 4; ++i) Av[i] = *(const float4*)&As[(ty4 + i) * 68 + kc];
        #pragma unroll
        for (int j = 0; j < 4; ++j) {
            L[j] = *(const float4*)&Bl[(kc + j) * 64 + tx4];
            R[j] = *(const float4*)&Br[(kc + j) * 64 + tx4];
        }
        #pragma unroll
        for (int i = 0; i < 4; ++i) {
            FMA4C(Av[i].x, L[0], accl[i]); FMA4C(Av[i].y, L[1], accl[i]);
            FMA4C(Av[i].z, L[2], accl[i]); FMA4C(Av[i].w, L[3], accl[i]);
            FMA4C(Av[i].x, R[0], accr[i]); FMA4C(Av[i].y, R[1], accr[i]);
            FMA4C(Av[i].z, R[2], accr[i]); FMA4C(Av[i].w, R[3], accr[i]);
        }
    }
    #pragma unroll
    for (int i = 0; i < 4; ++i) {
        int g = n0 + ty4 + i;
        if (g < NN) {
            *(float4*)&XL[(size_t)g * 64 + tx4] =
                make_float4(accl[i][0], accl[i][1], accl[i][2], accl[i][3]);
            *(float4*)&T[(size_t)g * 64 + tx4] =
                make_float4(accr[i][0] + b0, accr[i][1] + b1v, accr[i][2] + b2v, accr[i][3] + b3v);
            if (kc_out && tx4 == 60) {
                kc_out[g] = accl[i][3];
                tc_out[g] = accr[i][3] + b3v;
            }
        }
    }
}

__device__ __forceinline__ void stage_weights(float* Bl, float* Br,
        const float* __restrict__ Wl, const float* __restrict__ Wr, int t) {
    #pragma unroll
    for (int q = 0; q < 4; ++q) {
        int idx = t + q * 256;
        ((float4*)Bl)[idx] = ((const float4*)Wl)[idx];
        ((float4*)Br)[idx] = ((const float4*)Wr)[idx];
    }
}

// gemm over tile range [t0, t1), grid-stride with nblocks
__device__ __forceinline__ void gemm_body_range(int bid, int nblocks, int t0, int t1,
        float* smem, const float* __restrict__ X, const float* __restrict__ Wl,
        const float* __restrict__ Wr, const float* __restrict__ bias,
        float* __restrict__ XL, float* __restrict__ T) {
    float* As = smem;
    float* Bl = smem + 64 * 68;
    float* Br = Bl + 64 * 64;
    int t = threadIdx.x;
    stage_weights(Bl, Br, Wl, Wr, t);
    int ty4 = (t >> 4) * 4, tx4 = (t & 15) * 4;
    float b0 = bias[tx4 + 0], b1v = bias[tx4 + 1], b2v = bias[tx4 + 2], b3v = bias[tx4 + 3];
    for (int tile = t0 + bid; tile < t1; tile += nblocks) {
        int n0 = tile * 64;
        #pragma unroll
        for (int q = 0; q < 4; ++q) {
            int f = t + q * 256;
            int node = f >> 4, seg = f & 15;
            int g = n0 + node;
            float4 v = make_float4(0.f, 0.f, 0.f, 0.f);
            if (g < NN) v = *(const float4*)&X[(size_t)g * 64 + seg * 4];
            *(float4*)&As[node * 68 + seg * 4] = v;
        }
        __syncthreads();
        gemm_tile(As, Bl, Br, n0, ty4, tx4, b0, b1v, b2v, b3v, XL, T, nullptr, nullptr);
        __syncthreads();
    }
}

// ---------------- k1: bucket-count (transposed hist) || gstart ----------------
__global__ __launch_bounds__(256) void k_count(const int* __restrict__ edst,
        int* __restrict__ bh_t, const int* __restrict__ bat, int* __restrict__ gstart) {
    __shared__ int h[NBKT];
    int bid = blockIdx.x, t = threadIdx.x;
    if (bid < NL1B) {
        for (int q = t; q < NBKT; q += 256) h[q] = 0;
        __syncthreads();
        int e0 = bid * EPB, e1 = min(e0 + EPB, NE);
        for (int e = e0 + t; e < e1; e += 256) atomicAdd(&h[edst[e] >> 7], 1);
        __syncthreads();
        for (int q = t; q < NBKT; q += 256) bh_t[q * NL1B + bid] = h[q];
    } else {
        int g = (bid - NL1B) * 256 + t;
        if (g <= NG) {
            int lo = 0, hi = NN;
            while (lo < hi) { int mid = (lo + hi) >> 1; if (bat[mid] < g) lo = mid + 1; else hi = mid; }
            gstart[g] = lo;
        }
    }
}

// ---------------- k2: per-bucket scan across NL1B blocks (contiguous) ----------------
__global__ void k_colscan(int* __restrict__ bh_t, int* __restrict__ btot) {
    __shared__ int carry;
    int b = blockIdx.x, t = threadIdx.x;    // 64 threads
    if (t == 0) carry = 0;
    __syncthreads();
    for (int base = 0; base < NL1B; base += 64) {
        int idx = base + t;
        int v = (idx < NL1B) ? bh_t[b * NL1B + idx] : 0;
        int x = v;
        #pragma unroll
        for (int off = 1; off < 64; off <<= 1) {
            int y = __shfl_up(x, off);
            if (t >= off) x += y;
        }
        int c = carry;
        if (idx < NL1B) bh_t[b * NL1B + idx] = c + x - v;
        __syncthreads();
        if (t == 63) carry = c + x;
        __syncthreads();
    }
    if (t == 0) btot[b] = carry;
}

// ---------------- k3: bscatter || gemm1 tiles [0, TSPLIT) ----------------
__global__ __launch_bounds__(256) void k_scat_gemm(const int* __restrict__ esrc,
        const int* __restrict__ edst, const int* __restrict__ bh_t,
        const int* __restrict__ btot, int* __restrict__ ebuf,
        const float* __restrict__ X, const float* __restrict__ Wl,
        const float* __restrict__ Wr, const float* __restrict__ bias,
        float* __restrict__ XL, float* __restrict__ T) {
    __shared__ float smem[SMEM_FLOATS];
    int bid = blockIdx.x, t = threadIdx.x;
    if (bid < NL1B) {
        int* sbt  = (int*)smem;            // 1024
        int* ssum = sbt + 1024;            // 256
        int* cur  = ssum + 256;            // NBKT
        int bk = bid;
        for (int q = t; q < 1024; q += 256) sbt[q] = (q < NBKT) ? btot[q] : 0;
        __syncthreads();
        int base = t * 4;
        int a0 = sbt[base], a1 = sbt[base + 1], a2 = sbt[base + 2], a3 = sbt[base + 3];
        int s1 = a0 + a1, s2 = s1 + a2, s3 = s2 + a3;
        ssum[t] = s3;
        __syncthreads();
        for (int off = 1; off < 256; off <<= 1) {
            int y = (t >= off) ? ssum[t - off] : 0;
            __syncthreads();
            ssum[t] += y;
            __syncthreads();
        }
        int prev = (t > 0) ? ssum[t - 1] : 0;
        sbt[base] = prev; sbt[base + 1] = prev + a0;
        sbt[base + 2] = prev + s1; sbt[base + 3] = prev + s2;
        __syncthreads();
        for (int q = t; q < NBKT; q += 256) cur[q] = sbt[q] + bh_t[q * NL1B + bk];
        __syncthreads();
        int e0 = bk * EPB, e1 = min(e0 + EPB, NE);
        for (int e = e0 + t; e < e1; e += 256) {
            int d = edst[e], s = esrc[e];
            int pos = atomicAdd(&cur[d >> 7], 1);
            ebuf[pos] = s | ((d & 127) << 20);
        }
    } else {
        gemm_body_range(bid - NL1B, GB_HALF, 0, TSPLIT, smem, X, Wl, Wr, bias, XL, T);
    }
}

// ---------------- k4: bbuild (256-thread) || gemm1 tiles [TSPLIT, NTILES) ----------------
__global__ __launch_bounds__(256) void k_build_gemm(const int* __restrict__ ebuf,
        const int* __restrict__ btot, int* __restrict__ ce, int* __restrict__ ptr,
        const float* __restrict__ X, const float* __restrict__ Wl,
        const float* __restrict__ Wr, const float* __restrict__ bias,
        float* __restrict__ XL, float* __restrict__ T) {
    __shared__ float smem[SMEM_FLOATS];
    int bid = blockIdx.x, t = threadIdx.x;
    if (bid < NBKT) {
        int* lord   = (int*)smem;              // L2CAP
        int* cnt    = lord + L2CAP;            // BNODES
        int* sc     = cnt + BNODES;            // BNODES
        int* cursor = sc + BNODES;             // BNODES
        int* red    = cursor + BNODES;         // 256
        int b = bid;
        int part = 0;
        for (int j = t; j < b; j += 256) part += btot[j];
        red[t] = part;
        __syncthreads();
        for (int off = 128; off >= 1; off >>= 1) {
            if (t < off) red[t] += red[t + off];
            __syncthreads();
        }
        int base = red[0];
        int nb = btot[b];
        if (t < BNODES) cnt[t] = 0;
        __syncthreads();
        for (int j = t; j < nb; j += 256) atomicAdd(&cnt[ebuf[base + j] >> 20], 1);
        __syncthreads();
        int v = (t < BNODES) ? cnt[t] : 0;
        if (t < BNODES) sc[t] = v;
        __syncthreads();
        for (int off = 1; off < BNODES; off <<= 1) {
            int y = (t >= off && t < BNODES) ? sc[t - off] : 0;
            __syncthreads();
            if (t < BNODES) sc[t] += y;
            __syncthreads();
        }
        int segend = 0, segstart = 0;
        if (t < BNODES) { segend = sc[t]; segstart = sc[t] - v; cursor[t] = segstart; }
        __syncthreads();
        bool fits = (nb <= L2CAP);
        for (int j = t; j < nb; j += 256) {
            int pv = ebuf[base + j];
            int node = pv >> 20;
            int pos = atomicAdd(&cursor[node], 1);
            if (fits) lord[pos] = pv & 0xFFFFF;
            else ce[base + pos] = pv & 0xFFFFF;
        }
        __syncthreads();
        if (fits) {
            if (t < BNODES) {
                for (int a = segstart + 1; a < segend; ++a) {
                    int val = lord[a]; int j = a - 1;
                    while (j >= segstart && lord[j] > val) { lord[j + 1] = lord[j]; --j; }
                    lord[j + 1] = val;
                }
            }
            __syncthreads();
            for (int j = t; j < nb; j += 256) ce[base + j] = lord[j];
        } else {
            if (t < BNODES) {
                for (int a = segstart + 1; a < segend; ++a) {
                    int val = ce[base + a]; int j = a - 1;
                    while (j >= segstart && ce[base + j] > val) { ce[base + j + 1] = ce[base + j]; --j; }
                    ce[base + j + 1] = val;
                }
            }
        }
        if (t < BNODES) {
            int node = b * BNODES + t;
            if (node <= NN) ptr[node] = base + segstart;
        }
    } else {
        gemm_body_range(bid - NBKT, GB_HALF, TSPLIT, NTILES, smem, X, Wl, Wr, bias, XL, T);
    }
}

// ---------------- fused aggregate + dual GEMM (R9 config — best measured) ----------------
__global__ __launch_bounds__(256) void k_aggemm(const float* __restrict__ XL_in,
        float* __restrict__ T, const int* __restrict__ ptr, const int* __restrict__ ce,
        const float* __restrict__ Wl, const float* __restrict__ Wr,
        const float* __restrict__ bias, float* __restrict__ XL_out,
        float* __restrict__ kc_out, float* __restrict__ tc_out) {
    __shared__ float smem[SMEM_FLOATS];
    float* As = smem;
    float* Bl = smem + 64 * 68;
    float* Br = Bl + 64 * 64;
    int t = threadIdx.x;
    stage_weights(Bl, Br, Wl, Wr, t);
    int node_l = t >> 2;
    int fo = (t & 3) * 16;
    int ty4 = (t >> 4) * 4, tx4 = (t & 15) * 4;
    float b0 = bias[tx4 + 0], b1v = bias[tx4 + 1], b2v = bias[tx4 + 2], b3v = bias[tx4 + 3];
    for (int tile = blockIdx.x; tile < NTILES; tile += GEMM_BLOCKS) {
        int n0 = tile * 64;
        int i = n0 + node_l;
        float4 h0 = make_float4(0.f, 0.f, 0.f, 0.f), h1 = h0, h2 = h0, h3 = h0;
        if (i < NN) {
            int s = ptr[i], e = ptr[i + 1];
            agg_node(XL_in, ce, s, e, fo, h0, h1, h2, h3);
            float inv = 1.f / fmaxf((float)(e - s), 1.f);
            relu_mean_res(inv, (const float4*)(T + ((size_t)i << 6) + fo), h0, h1, h2, h3);
        }
        float* dst = &As[node_l * 68 + fo];
        ((float4*)dst)[0] = h0; ((float4*)dst)[1] = h1;
        ((float4*)dst)[2] = h2; ((float4*)dst)[3] = h3;
        __syncthreads();
        gemm_tile(As, Bl, Br, n0, ty4, tx4, b0, b1v, b2v, b3v, XL_out, T, kc_out, tc_out);
        __syncthreads();
    }
}

// ---------------- tail: key + top-7 + winner-row aggregate + head ----------------
__global__ __launch_bounds__(256) void k_tail(const int* __restrict__ gstart,
        const float* __restrict__ keycol, const float* __restrict__ tcol,
        const int* __restrict__ ptr, const int* __restrict__ ce,
        const float* __restrict__ XLa, const float* __restrict__ T,
        const float* __restrict__ cw, const float* __restrict__ cb,
        const float* __restrict__ l1w, const float* __restrict__ l1b,
        const float* __restrict__ l2w, const float* __restrict__ l2b,
        float* __restrict__ out, int G) {
    __shared__ float sw[32 * 64 * 3];
    __shared__ float s2w[64 * 10];
    __shared__ float sg[4][KTOP][64];
    __shared__ float sflat[4][160];
    __shared__ float sh1[4][64];
    __shared__ float slog[4][10];
    __shared__ float skey[4][KCAP];
    __shared__ int   widx[4][KTOP];
    int t = threadIdx.x;
    for (int q = t; q < 32 * 64 * 3; q += 256) sw[q] = cw[q];
    for (int q = t; q < 640; q += 256) s2w[q] = l2w[q];
    int wv = t >> 6, lane = t & 63;
    int b = blockIdx.x * 4 + wv;
    int s = gstart[b], e = gstart[b + 1];
    int cnt = e - s;
    for (int base = 0; base < cnt; base += 64) {
        int o = base + lane;
        if (o < cnt && o < KCAP) skey[wv][o] = compute_key(s + o, keycol, tcol, ptr, ce);
    }
    {
        float pk = 3.4e38f; int pi = -1;
        for (int r = 0; r < KTOP; ++r) {
            float bk = -1.f; int bi = -1;
            for (int o = lane; o < cnt; o += 64) {
                int i = s + o;
                float k = (o < KCAP) ? skey[wv][o] : compute_key(i, keycol, tcol, ptr, ce);
                bool elig = (k < pk) || (k == pk && i > pi);
                if (elig && (k > bk || (k == bk && (unsigned)i < (unsigned)bi))) { bk = k; bi = i; }
            }
            #pragma unroll
            for (int off = 1; off < 64; off <<= 1) {
                float ok = __shfl_xor(bk, off);
                int   oi = __shfl_xor(bi, off);
                if (ok > bk || (ok == bk && (unsigned)oi < (unsigned)bi)) { bk = ok; bi = oi; }
            }
            if (lane == 0) widx[wv][r] = bi;
            pk = bk; pi = bi;
        }
    }
    if (lane < 28) {
        int r = lane >> 2, fo = (lane & 3) * 16;
        int i = widx[wv][r];
        float4 h0 = make_float4(0.f, 0.f, 0.f, 0.f), h1 = h0, h2 = h0, h3 = h0;
        if (i >= 0) {
            int s2 = ptr[i], e2 = ptr[i + 1];
            agg_node(XLa, ce, s2, e2, fo, h0, h1, h2, h3);
            float inv = 1.f / fmaxf((float)(e2 - s2), 1.f);
            relu_mean_res(inv, (const float4*)(T + ((size_t)i << 6) + fo), h0, h1, h2, h3);
        }
        float* dstp = &sg[wv][r][fo];
        ((float4*)dstp)[0] = h0; ((float4*)dstp)[1] = h1;
        ((float4*)dstp)[2] = h2; ((float4*)dstp)[3] = h3;
    }
    __syncthreads();
    for (int idx = lane; idx < 160; idx += 64) {
        int o = idx / 5, p = idx % 5;
        float acc = cb[o];
        #pragma unroll
        for (int dt = 0; dt < 3; ++dt) {
            const float* wrow = &sw[(o * 64) * 3 + dt];
            const float* grow = &sg[wv][p + dt][0];
            for (int i = 0; i < 64; ++i) acc = fmaf(wrow[i * 3], grow[i], acc);
        }
        sflat[wv][idx] = fmaxf(acc, 0.f);
    }
    __syncthreads();
    {
        float acc = l1b[lane];
        for (int k = 0; k < 160; ++k) acc = fmaf(sflat[wv][k], l1w[k * 64 + lane], acc);
        sh1[wv][lane] = fmaxf(acc, 0.f);
    }
    __syncthreads();
    if (lane < 10) {
        float acc = l2b[lane];
        for (int k = 0; k < 64; ++k) acc = fmaf(sh1[wv][k], s2w[k * 10 + lane], acc);
        slog[wv][lane] = acc;
    }
    __syncthreads();
    if (lane < 10) {
        float m = -3.4e38f;
        for (int j = 0; j < 10; ++j) m = fmaxf(m, slog[wv][j]);
        float ssum = 0.f;
        for (int j = 0; j < 10; ++j) ssum += expf(slog[wv][j] - m);
        out[b * 10 + lane] = slog[wv][lane] - m - logf(ssum);
    }
}

extern "C" void kernel_launch(void* const* d_in, const int* in_sizes, int n_in,
                              void* d_out, int out_size, void* d_ws, size_t ws_size,
                              hipStream_t stream) {
    const float* x   = (const float*)d_in[0];
    const int*   ei  = (const int*)d_in[1];
    const int*   bat = (const int*)d_in[2];
    const float* W1l = (const float*)d_in[3], *b1 = (const float*)d_in[4], *W1r = (const float*)d_in[5];
    const float* W2l = (const float*)d_in[6], *b2 = (const float*)d_in[7], *W2r = (const float*)d_in[8];
    const float* W3l = (const float*)d_in[9], *b3 = (const float*)d_in[10], *W3r = (const float*)d_in[11];
    const float* cw  = (const float*)d_in[12], *cb  = (const float*)d_in[13];
    const float* l1w = (const float*)d_in[14], *l1b = (const float*)d_in[15];
    const float* l2w = (const float*)d_in[16], *l2b = (const float*)d_in[17];
    float* out = (float*)d_out;
    const int* esrc = ei;
    const int* edst = ei + NE;

    char* w = (char*)d_ws;
    size_t off = 0;
    auto take = [&](size_t bytes) { void* p = w + off; off = (off + bytes + 255) & ~(size_t)255; return p; };
    int*   bh_t    = (int*)take((size_t)NBKT * NL1B * 4);
    int*   btot    = (int*)take((size_t)NBKT * 4);
    int*   gstart  = (int*)take((size_t)(NG + 1) * 4);
    int*   ebuf    = (int*)take((size_t)NE * 4);
    int*   csr_ptr = (int*)take((size_t)(NN + 1) * 4);
    int*   csr_e   = (int*)take((size_t)NE * 4);
    float* XLa     = (float*)take((size_t)NN * 64 * 4);
    float* XLb     = (float*)take((size_t)NN * 64 * 4);
    float* T       = (float*)take((size_t)NN * 64 * 4);
    float* keycol  = (float*)take((size_t)NN * 4);
    float* tcol    = (float*)take((size_t)NN * 4);

    // k1: bucket-count || gstart
    k_count<<<NL1B + 8, 256, 0, stream>>>(edst, bh_t, bat, gstart);
    // k2: column scan
    k_colscan<<<NBKT, 64, 0, stream>>>(bh_t, btot);
    // k3: bscatter || gemm1 first tiles
    k_scat_gemm<<<NL1B + GB_HALF, 256, 0, stream>>>(esrc, edst, bh_t, btot, ebuf,
                                                    x, W1l, W1r, b1, XLa, T);
    // k4: bbuild || gemm1 remaining tiles
    k_build_gemm<<<NBKT + GB_HALF, 256, 0, stream>>>(ebuf, btot, csr_e, csr_ptr,
                                                     x, W1l, W1r, b1, XLa, T);

    // layer boundaries: aggregate + dual gemm (R9 config)
    k_aggemm<<<GEMM_BLOCKS, 256, 0, stream>>>(XLa, T, csr_ptr, csr_e, W2l, W2r, b2, XLb,
                                              nullptr, nullptr);
    k_aggemm<<<GEMM_BLOCKS, 256, 0, stream>>>(XLb, T, csr_ptr, csr_e, W3l, W3r, b3, XLa,
                                              keycol, tcol);

    // tail
    k_tail<<<NG / 4, 256, 0, stream>>>(gstart, keycol, tcol, csr_ptr, csr_e, XLa, T,
                                       cw, cb, l1w, l1b, l2w, l2b, out, NG);
}

// Round 12
// 318.465 us; speedup vs baseline: 1.0595x; 1.0466x over previous
//
#include <hip/hip_runtime.h>
#include <hip/hip_bf16.h>

#define NN 100000
#define NE 1600000
#define NG 2000
#define KTOP 7
#define KCAP 192                   // per-graph key cache (max graph ~87 nodes; 20 sigma)

#define BNODES 128                 // nodes per bucket
#define NBKT 782                   // ceil(NN/128)
#define EPB 8192                   // edges per level-1 block
#define NL1B 196                   // ceil(NE/EPB)
#define L2CAP 4096                 // LDS edge capacity in level-2 build

#define GEMM_BLOCKS 768            // grid-stride gemm/aggemm: 3 blocks/CU (49 KB LDS)
#define NTILES 1563                // ceil(NN/64)
#define SMEM_FLOATS (64 * 68 + 2 * 64 * 64)   // As + Bl + Br = 50176 B

#define ACC4(A, V) do { A.x += V.x; A.y += V.y; A.z += V.z; A.w += V.w; } while (0)
#define ACC4P(A, U, W) do { A.x += U.x + W.x; A.y += U.y + W.y; \
                            A.z += U.z + W.z; A.w += U.w + W.w; } while (0)

// per-node aggregate: this thread owns features [fo, fo+16); 2-edge unroll = 8 loads in flight
__device__ __forceinline__ void agg_node(const float* __restrict__ XLp, const int* __restrict__ ce,
        int s, int e, int fo, float4& a0, float4& a1, float4& a2, float4& a3) {
    int a = s;
    for (; a + 2 <= e; a += 2) {
        const float4* p0 = (const float4*)(XLp + ((size_t)ce[a] << 6) + fo);
        const float4* p1 = (const float4*)(XLp + ((size_t)ce[a + 1] << 6) + fo);
        float4 u0 = p0[0], u1 = p0[1], u2 = p0[2], u3 = p0[3];
        float4 w0 = p1[0], w1 = p1[1], w2 = p1[2], w3 = p1[3];
        ACC4P(a0, u0, w0); ACC4P(a1, u1, w1); ACC4P(a2, u2, w2); ACC4P(a3, u3, w3);
    }
    if (a < e) {
        const float4* p0 = (const float4*)(XLp + ((size_t)ce[a] << 6) + fo);
        float4 u0 = p0[0], u1 = p0[1], u2 = p0[2], u3 = p0[3];
        ACC4(a0, u0); ACC4(a1, u1); ACC4(a2, u2); ACC4(a3, u3);
    }
}

// relu(mean + residual) on 4x float4 — formula must stay bit-identical across kernels
__device__ __forceinline__ void relu_mean_res(float inv, const float4* tp,
        float4& h0, float4& h1, float4& h2, float4& h3) {
    float4 t0 = tp[0], t1 = tp[1], t2 = tp[2], t3 = tp[3];
    h0.x = fmaxf(h0.x * inv + t0.x, 0.f); h0.y = fmaxf(h0.y * inv + t0.y, 0.f);
    h0.z = fmaxf(h0.z * inv + t0.z, 0.f); h0.w = fmaxf(h0.w * inv + t0.w, 0.f);
    h1.x = fmaxf(h1.x * inv + t1.x, 0.f); h1.y = fmaxf(h1.y * inv + t1.y, 0.f);
    h1.z = fmaxf(h1.z * inv + t1.z, 0.f); h1.w = fmaxf(h1.w * inv + t1.w, 0.f);
    h2.x = fmaxf(h2.x * inv + t2.x, 0.f); h2.y = fmaxf(h2.y * inv + t2.y, 0.f);
    h2.z = fmaxf(h2.z * inv + t2.z, 0.f); h2.w = fmaxf(h2.w * inv + t2.w, 0.f);
    h3.x = fmaxf(h3.x * inv + t3.x, 0.f); h3.y = fmaxf(h3.y * inv + t3.y, 0.f);
    h3.z = fmaxf(h3.z * inv + t3.z, 0.f); h3.w = fmaxf(h3.w * inv + t3.w, 0.f);
}

// key for node i from packed col-63 arrays; order matches agg_node's .w lane exactly
__device__ __forceinline__ float compute_key(int i, const float* __restrict__ keycol,
        const float* __restrict__ tcol, const int* __restrict__ ptr,
        const int* __restrict__ ce) {
    int s = ptr[i], e = ptr[i + 1];
    float acc = 0.f;
    int a = s;
    for (; a + 2 <= e; a += 2) acc += keycol[ce[a]] + keycol[ce[a + 1]];
    if (a < e) acc += keycol[ce[a]];
    float inv = 1.f / fmaxf((float)(e - s), 1.f);
    return fmaxf(acc * inv + tcol[i], 0.f);
}

#define FMA4C(av, B, acc) do { \
    acc[0] = fmaf(av, B.x, acc[0]); acc[1] = fmaf(av, B.y, acc[1]); \
    acc[2] = fmaf(av, B.z, acc[2]); acc[3] = fmaf(av, B.w, acc[3]); } while (0)

// dual GEMM tile, LDS A + LDS weights
__device__ __forceinline__ void gemm_tile(const float* As, const float* Bl, const float* Br,
        int n0, int ty4, int tx4, float b0, float b1v, float b2v, float b3v,
        float* __restrict__ XL, float* __restrict__ T,
        float* __restrict__ kc_out, float* __restrict__ tc_out) {
    float accl[4][4] = {{0.f}}, accr[4][4] = {{0.f}};
    for (int kc = 0; kc < 64; kc += 4) {
        float4 Av[4], L[4], R[4];
        #pragma unroll
        for (int i = 0; i < 4; ++i) Av[i] = *(const float4*)&As[(ty4 + i) * 68 + kc];
        #pragma unroll
        for (int j = 0; j < 4; ++j) {
            L[j] = *(const float4*)&Bl[(kc + j) * 64 + tx4];
            R[j] = *(const float4*)&Br[(kc + j) * 64 + tx4];
        }
        #pragma unroll
        for (int i = 0; i < 4; ++i) {
            FMA4C(Av[i].x, L[0], accl[i]); FMA4C(Av[i].y, L[1], accl[i]);
            FMA4C(Av[i].z, L[2], accl[i]); FMA4C(Av[i].w, L[3], accl[i]);
            FMA4C(Av[i].x, R[0], accr[i]); FMA4C(Av[i].y, R[1], accr[i]);
            FMA4C(Av[i].z, R[2], accr[i]); FMA4C(Av[i].w, R[3], accr[i]);
        }
    }
    #pragma unroll
    for (int i = 0; i < 4; ++i) {
        int g = n0 + ty4 + i;
        if (g < NN) {
            *(float4*)&XL[(size_t)g * 64 + tx4] =
                make_float4(accl[i][0], accl[i][1], accl[i][2], accl[i][3]);
            *(float4*)&T[(size_t)g * 64 + tx4] =
                make_float4(accr[i][0] + b0, accr[i][1] + b1v, accr[i][2] + b2v, accr[i][3] + b3v);
            if (kc_out && tx4 == 60) {
                kc_out[g] = accl[i][3];
                tc_out[g] = accr[i][3] + b3v;
            }
        }
    }
}

__device__ __forceinline__ void stage_weights(float* Bl, float* Br,
        const float* __restrict__ Wl, const float* __restrict__ Wr, int t) {
    #pragma unroll
    for (int q = 0; q < 4; ++q) {
        int idx = t + q * 256;
        ((float4*)Bl)[idx] = ((const float4*)Wl)[idx];
        ((float4*)Br)[idx] = ((const float4*)Wr)[idx];
    }
}

__device__ __forceinline__ void gemm_body(int bid, int nblocks, float* smem,
        const float* __restrict__ X, const float* __restrict__ Wl,
        const float* __restrict__ Wr, const float* __restrict__ bias,
        float* __restrict__ XL, float* __restrict__ T) {
    float* As = smem;
    float* Bl = smem + 64 * 68;
    float* Br = Bl + 64 * 64;
    int t = threadIdx.x;
    stage_weights(Bl, Br, Wl, Wr, t);
    int ty4 = (t >> 4) * 4, tx4 = (t & 15) * 4;
    float b0 = bias[tx4 + 0], b1v = bias[tx4 + 1], b2v = bias[tx4 + 2], b3v = bias[tx4 + 3];
    for (int tile = bid; tile < NTILES; tile += nblocks) {
        int n0 = tile * 64;
        #pragma unroll
        for (int q = 0; q < 4; ++q) {
            int f = t + q * 256;
            int node = f >> 4, seg = f & 15;
            int g = n0 + node;
            float4 v = make_float4(0.f, 0.f, 0.f, 0.f);
            if (g < NN) v = *(const float4*)&X[(size_t)g * 64 + seg * 4];
            *(float4*)&As[node * 68 + seg * 4] = v;
        }
        __syncthreads();
        gemm_tile(As, Bl, Br, n0, ty4, tx4, b0, b1v, b2v, b3v, XL, T, nullptr, nullptr);
        __syncthreads();
    }
}

// ---------------- fused aggregate + dual GEMM (best measured config) ----------------
__global__ __launch_bounds__(256) void k_aggemm(const float* __restrict__ XL_in,
        float* __restrict__ T, const int* __restrict__ ptr, const int* __restrict__ ce,
        const float* __restrict__ Wl, const float* __restrict__ Wr,
        const float* __restrict__ bias, float* __restrict__ XL_out,
        float* __restrict__ kc_out, float* __restrict__ tc_out) {
    __shared__ float smem[SMEM_FLOATS];
    float* As = smem;
    float* Bl = smem + 64 * 68;
    float* Br = Bl + 64 * 64;
    int t = threadIdx.x;
    stage_weights(Bl, Br, Wl, Wr, t);
    int node_l = t >> 2;           // 0..63
    int fo = (t & 3) * 16;
    int ty4 = (t >> 4) * 4, tx4 = (t & 15) * 4;
    float b0 = bias[tx4 + 0], b1v = bias[tx4 + 1], b2v = bias[tx4 + 2], b3v = bias[tx4 + 3];
    for (int tile = blockIdx.x; tile < NTILES; tile += GEMM_BLOCKS) {
        int n0 = tile * 64;
        int i = n0 + node_l;
        float4 h0 = make_float4(0.f, 0.f, 0.f, 0.f), h1 = h0, h2 = h0, h3 = h0;
        if (i < NN) {
            int s = ptr[i], e = ptr[i + 1];
            agg_node(XL_in, ce, s, e, fo, h0, h1, h2, h3);
            float inv = 1.f / fmaxf((float)(e - s), 1.f);
            relu_mean_res(inv, (const float4*)(T + ((size_t)i << 6) + fo), h0, h1, h2, h3);
        }
        float* dst = &As[node_l * 68 + fo];
        ((float4*)dst)[0] = h0; ((float4*)dst)[1] = h1;
        ((float4*)dst)[2] = h2; ((float4*)dst)[3] = h3;
        __syncthreads();
        gemm_tile(As, Bl, Br, n0, ty4, tx4, b0, b1v, b2v, b3v, XL_out, T, kc_out, tc_out);
        __syncthreads();
    }
}

// ---------------- front mega-kernel: gemm1 || bucket-count(transposed) || gstart ----------------
__global__ __launch_bounds__(256) void k_front(const float* __restrict__ X,
        const float* __restrict__ Wl, const float* __restrict__ Wr,
        const float* __restrict__ bias, float* __restrict__ XL, float* __restrict__ T,
        const int* __restrict__ edst, int* __restrict__ bh_t,
        const int* __restrict__ bat, int* __restrict__ gstart) {
    __shared__ float smem[SMEM_FLOATS];
    int bid = blockIdx.x, t = threadIdx.x;
    if (bid < GEMM_BLOCKS) {
        gemm_body(bid, GEMM_BLOCKS, smem, X, Wl, Wr, bias, XL, T);
    } else if (bid < GEMM_BLOCKS + NL1B) {
        int bk = bid - GEMM_BLOCKS;
        int* h = (int*)smem;
        for (int q = t; q < NBKT; q += 256) h[q] = 0;
        __syncthreads();
        int e0 = bk * EPB, e1 = min(e0 + EPB, NE);
        for (int e = e0 + t; e < e1; e += 256) atomicAdd(&h[edst[e] >> 7], 1);
        __syncthreads();
        for (int q = t; q < NBKT; q += 256) bh_t[q * NL1B + bk] = h[q];   // transposed
    } else {
        int g = (bid - GEMM_BLOCKS - NL1B) * 256 + t;
        if (g <= NG) {
            int lo = 0, hi = NN;
            while (lo < hi) { int mid = (lo + hi) >> 1; if (bat[mid] < g) lo = mid + 1; else hi = mid; }
            gstart[g] = lo;
        }
    }
}

// per-bucket scan across NL1B blocks — contiguous reads
__global__ void k_colscan(int* __restrict__ bh_t, int* __restrict__ btot) {
    __shared__ int carry;
    int b = blockIdx.x, t = threadIdx.x;    // 64 threads
    if (t == 0) carry = 0;
    __syncthreads();
    for (int base = 0; base < NL1B; base += 64) {
        int idx = base + t;
        int v = (idx < NL1B) ? bh_t[b * NL1B + idx] : 0;
        int x = v;
        #pragma unroll
        for (int off = 1; off < 64; off <<= 1) {
            int y = __shfl_up(x, off);
            if (t >= off) x += y;
        }
        int c = carry;
        if (idx < NL1B) bh_t[b * NL1B + idx] = c + x - v;   // exclusive partial
        __syncthreads();
        if (t == 63) carry = c + x;
        __syncthreads();
    }
    if (t == 0) btot[b] = carry;
}

// level-1 scatter: computes bstart scan in-LDS from btot
__global__ __launch_bounds__(256) void k_bscatter(const int* __restrict__ esrc,
        const int* __restrict__ edst, const int* __restrict__ bh_t,
        const int* __restrict__ btot, int* __restrict__ ebuf) {
    __shared__ int sbt[1024];
    __shared__ int ssum[256];
    __shared__ int cur[NBKT];
    int t = threadIdx.x, bk = blockIdx.x;
    for (int q = t; q < 1024; q += 256) sbt[q] = (q < NBKT) ? btot[q] : 0;
    __syncthreads();
    int base = t * 4;
    int a0 = sbt[base], a1 = sbt[base + 1], a2 = sbt[base + 2], a3 = sbt[base + 3];
    int s1 = a0 + a1, s2 = s1 + a2, s3 = s2 + a3;
    ssum[t] = s3;
    __syncthreads();
    for (int off = 1; off < 256; off <<= 1) {
        int y = (t >= off) ? ssum[t - off] : 0;
        __syncthreads();
        ssum[t] += y;
        __syncthreads();
    }
    int prev = (t > 0) ? ssum[t - 1] : 0;
    sbt[base] = prev; sbt[base + 1] = prev + a0;
    sbt[base + 2] = prev + s1; sbt[base + 3] = prev + s2;
    __syncthreads();
    for (int q = t; q < NBKT; q += 256) cur[q] = sbt[q] + bh_t[q * NL1B + bk];
    __syncthreads();
    int e0 = bk * EPB, e1 = min(e0 + EPB, NE);
    for (int e = e0 + t; e < e1; e += 256) {
        int d = edst[e], s = esrc[e];
        int pos = atomicAdd(&cur[d >> 7], 1);
        ebuf[pos] = s | ((d & 127) << 20);
    }
}

// level-2: per-bucket count/scan/place/sort in LDS; bstart prefix computed in-block
__global__ __launch_bounds__(128) void k_bbuild(const int* __restrict__ ebuf,
        const int* __restrict__ btot, int* __restrict__ ce, int* __restrict__ ptr) {
    __shared__ int lord[L2CAP];
    __shared__ int cnt[BNODES], sc[BNODES], cursor[BNODES];
    __shared__ int red[128];
    int b = blockIdx.x, t = threadIdx.x;     // 128 threads
    int part = 0;
    for (int j = t; j < b; j += 128) part += btot[j];
    red[t] = part;
    __syncthreads();
    for (int off = 64; off >= 1; off >>= 1) {
        if (t < off) red[t] += red[t + off];
        __syncthreads();
    }
    int base = red[0];
    int nb = btot[b];
    cnt[t] = 0;
    __syncthreads();
    for (int j = t; j < nb; j += 128) atomicAdd(&cnt[ebuf[base + j] >> 20], 1);
    __syncthreads();
    int v = cnt[t]; sc[t] = v; __syncthreads();
    for (int off = 1; off < 128; off <<= 1) {
        int y = (t >= off) ? sc[t - off] : 0;
        __syncthreads();
        sc[t] += y;
        __syncthreads();
    }
    int segend = sc[t], segstart = sc[t] - v;
    cursor[t] = segstart;
    __syncthreads();
    bool fits = (nb <= L2CAP);
    for (int j = t; j < nb; j += 128) {
        int pv = ebuf[base + j];
        int node = pv >> 20;
        int pos = atomicAdd(&cursor[node], 1);
        if (fits) lord[pos] = pv & 0xFFFFF;
        else ce[base + pos] = pv & 0xFFFFF;
    }
    __syncthreads();
    if (fits) {
        for (int a = segstart + 1; a < segend; ++a) {
            int val = lord[a]; int j = a - 1;
            while (j >= segstart && lord[j] > val) { lord[j + 1] = lord[j]; --j; }
            lord[j + 1] = val;
        }
        __syncthreads();
        for (int j = t; j < nb; j += 128) ce[base + j] = lord[j];
    } else {
        for (int a = segstart + 1; a < segend; ++a) {
            int val = ce[base + a]; int j = a - 1;
            while (j >= segstart && ce[base + j] > val) { ce[base + j + 1] = ce[base + j]; --j; }
            ce[base + j + 1] = val;
        }
    }
    int node = b * BNODES + t;
    if (node <= NN) ptr[node] = base + segstart;
}

// ---------------- tail: key + top-7 + winner-row aggregate + head, fully fused ----------------
__global__ __launch_bounds__(256) void k_tail(const int* __restrict__ gstart,
        const float* __restrict__ keycol, const float* __restrict__ tcol,
        const int* __restrict__ ptr, const int* __restrict__ ce,
        const float* __restrict__ XLa, const float* __restrict__ T,
        const float* __restrict__ cw, const float* __restrict__ cb,
        const float* __restrict__ l1w, const float* __restrict__ l1b,
        const float* __restrict__ l2w, const float* __restrict__ l2b,
        float* __restrict__ out, int G) {
    __shared__ float sw[32 * 64 * 3];
    __shared__ float s2w[64 * 10];
    __shared__ float sg[4][KTOP][64];
    __shared__ float sflat[4][160];
    __shared__ float sh1[4][64];
    __shared__ float slog[4][10];
    __shared__ float skey[4][KCAP];
    __shared__ int   widx[4][KTOP];
    int t = threadIdx.x;
    for (int q = t; q < 32 * 64 * 3; q += 256) sw[q] = cw[q];
    for (int q = t; q < 640; q += 256) s2w[q] = l2w[q];
    int wv = t >> 6, lane = t & 63;
    int b = blockIdx.x * 4 + wv;
    int s = gstart[b], e = gstart[b + 1];
    int cnt = e - s;
    for (int base = 0; base < cnt; base += 64) {
        int o = base + lane;
        if (o < cnt && o < KCAP) skey[wv][o] = compute_key(s + o, keycol, tcol, ptr, ce);
    }
    {
        float pk = 3.4e38f; int pi = -1;
        for (int r = 0; r < KTOP; ++r) {
            float bk = -1.f; int bi = -1;
            for (int o = lane; o < cnt; o += 64) {
                int i = s + o;
                float k = (o < KCAP) ? skey[wv][o] : compute_key(i, keycol, tcol, ptr, ce);
                bool elig = (k < pk) || (k == pk && i > pi);
                if (elig && (k > bk || (k == bk && (unsigned)i < (unsigned)bi))) { bk = k; bi = i; }
            }
            #pragma unroll
            for (int off = 1; off < 64; off <<= 1) {
                float ok = __shfl_xor(bk, off);
                int   oi = __shfl_xor(bi, off);
                if (ok > bk || (ok == bk && (unsigned)oi < (unsigned)bi)) { bk = ok; bi = oi; }
            }
            if (lane == 0) widx[wv][r] = bi;
            pk = bk; pi = bi;
        }
    }
    if (lane < 28) {
        int r = lane >> 2, fo = (lane & 3) * 16;
        int i = widx[wv][r];
        float4 h0 = make_float4(0.f, 0.f, 0.f, 0.f), h1 = h0, h2 = h0, h3 = h0;
        if (i >= 0) {
            int s2 = ptr[i], e2 = ptr[i + 1];
            agg_node(XLa, ce, s2, e2, fo, h0, h1, h2, h3);
            float inv = 1.f / fmaxf((float)(e2 - s2), 1.f);
            relu_mean_res(inv, (const float4*)(T + ((size_t)i << 6) + fo), h0, h1, h2, h3);
        }
        float* dstp = &sg[wv][r][fo];
        ((float4*)dstp)[0] = h0; ((float4*)dstp)[1] = h1;
        ((float4*)dstp)[2] = h2; ((float4*)dstp)[3] = h3;
    }
    __syncthreads();
    for (int idx = lane; idx < 160; idx += 64) {
        int o = idx / 5, p = idx % 5;
        float acc = cb[o];
        #pragma unroll
        for (int dt = 0; dt < 3; ++dt) {
            const float* wrow = &sw[(o * 64) * 3 + dt];
            const float* grow = &sg[wv][p + dt][0];
            for (int i = 0; i < 64; ++i) acc = fmaf(wrow[i * 3], grow[i], acc);
        }
        sflat[wv][idx] = fmaxf(acc, 0.f);
    }
    __syncthreads();
    {
        float acc = l1b[lane];
        for (int k = 0; k < 160; ++k) acc = fmaf(sflat[wv][k], l1w[k * 64 + lane], acc);
        sh1[wv][lane] = fmaxf(acc, 0.f);
    }
    __syncthreads();
    if (lane < 10) {
        float acc = l2b[lane];
        for (int k = 0; k < 64; ++k) acc = fmaf(sh1[wv][k], s2w[k * 10 + lane], acc);
        slog[wv][lane] = acc;
    }
    __syncthreads();
    if (lane < 10) {
        float m = -3.4e38f;
        for (int j = 0; j < 10; ++j) m = fmaxf(m, slog[wv][j]);
        float ssum = 0.f;
        for (int j = 0; j < 10; ++j) ssum += expf(slog[wv][j] - m);
        out[b * 10 + lane] = slog[wv][lane] - m - logf(ssum);
    }
}

extern "C" void kernel_launch(void* const* d_in, const int* in_sizes, int n_in,
                              void* d_out, int out_size, void* d_ws, size_t ws_size,
                              hipStream_t stream) {
    const float* x   = (const float*)d_in[0];
    const int*   ei  = (const int*)d_in[1];
    const int*   bat = (const int*)d_in[2];
    const float* W1l = (const float*)d_in[3], *b1 = (const float*)d_in[4], *W1r = (const float*)d_in[5];
    const float* W2l = (const float*)d_in[6], *b2 = (const float*)d_in[7], *W2r = (const float*)d_in[8];
    const float* W3l = (const float*)d_in[9], *b3 = (const float*)d_in[10], *W3r = (const float*)d_in[11];
    const float* cw  = (const float*)d_in[12], *cb  = (const float*)d_in[13];
    const float* l1w = (const float*)d_in[14], *l1b = (const float*)d_in[15];
    const float* l2w = (const float*)d_in[16], *l2b = (const float*)d_in[17];
    float* out = (float*)d_out;
    const int* esrc = ei;
    const int* edst = ei + NE;

    char* w = (char*)d_ws;
    size_t off = 0;
    auto take = [&](size_t bytes) { void* p = w + off; off = (off + bytes + 255) & ~(size_t)255; return p; };
    int*   bh_t    = (int*)take((size_t)NBKT * NL1B * 4);
    int*   btot    = (int*)take((size_t)NBKT * 4);
    int*   gstart  = (int*)take((size_t)(NG + 1) * 4);
    int*   ebuf    = (int*)take((size_t)NE * 4);
    int*   csr_ptr = (int*)take((size_t)(NN + 1) * 4);
    int*   csr_e   = (int*)take((size_t)NE * 4);
    float* XLa     = (float*)take((size_t)NN * 64 * 4);
    float* XLb     = (float*)take((size_t)NN * 64 * 4);
    float* T       = (float*)take((size_t)NN * 64 * 4);   // residual, in place
    float* keycol  = (float*)take((size_t)NN * 4);        // XLa col 63, packed
    float* tcol    = (float*)take((size_t)NN * 4);        // T col 63, packed

    // gemm1 || bucket-count || gstart
    k_front<<<GEMM_BLOCKS + NL1B + 8, 256, 0, stream>>>(x, W1l, W1r, b1, XLa, T,
                                                        edst, bh_t, bat, gstart);
    k_colscan<<<NBKT, 64, 0, stream>>>(bh_t, btot);
    k_bscatter<<<NL1B, 256, 0, stream>>>(esrc, edst, bh_t, btot, ebuf);
    k_bbuild <<<NBKT, 128, 0, stream>>>(ebuf, btot, csr_e, csr_ptr);

    // layer boundaries: aggregate (H in LDS) + dual gemm; T updated in place
    k_aggemm<<<GEMM_BLOCKS, 256, 0, stream>>>(XLa, T, csr_ptr, csr_e, W2l, W2r, b2, XLb,
                                              nullptr, nullptr);
    k_aggemm<<<GEMM_BLOCKS, 256, 0, stream>>>(XLb, T, csr_ptr, csr_e, W3l, W3r, b3, XLa,
                                              keycol, tcol);

    // key + top-7 + winner aggregate + head, one kernel
    k_tail<<<NG / 4, 256, 0, stream>>>(gstart, keycol, tcol, csr_ptr, csr_e, XLa, T,
                                       cw, cb, l1w, l1b, l2w, l2b, out, NG);
}